// Round 24
// baseline (533.049 us; speedup 1.0000x reference)
//
#include <hip/hip_runtime.h>

#define EMBD 50
#define HID 50
#define BLK 256             // block size for prep/fallback kernels
#define MBLK 1024           // main kernel: 16 waves/block -> 4 waves/SIMD forced
#define NT 13               // gate tiles: 13*16 = 208 rows >= 200 real gates
#define LOG2E 1.44269504f

typedef float f32x4 __attribute__((ext_vector_type(4)));
typedef short short8 __attribute__((ext_vector_type(8)));
typedef unsigned u32x4 __attribute__((ext_vector_type(4)));

__device__ __forceinline__ int imax(int a, int b) { return a > b ? a : b; }
__device__ __forceinline__ int imin(int a, int b) { return a < b ? a : b; }

__device__ __forceinline__ unsigned short f2bf(float f) {
    unsigned u = __float_as_uint(f);
    u += 0x7FFFu + ((u >> 16) & 1u);
    return (unsigned short)(u >> 16);
}
__device__ __forceinline__ unsigned cvtpk(float a, float b) {
    unsigned r;
    asm("v_cvt_pk_bf16_f32 %0, %1, %2" : "=v"(r) : "v"(a), "v"(b));
    return r;
}
// (fallback only)
__device__ __forceinline__ float sigm(float x) {
    return __fdividef(1.0f, 1.0f + __expf(-x));
}
__device__ __forceinline__ float tanhfast(float x) {
    float e = __expf(2.0f * x);
    return 1.0f - __fdividef(2.0f, e + 1.0f);
}

// ---------------- length bucket sort ----------------
__global__ void zero_counts_kernel(int* ws) {
    if (threadIdx.x < 75) ws[threadIdx.x] = 0;
}
__global__ void hist_kernel(const int* __restrict__ lengths, int* ws, int nw) {
    __shared__ int lc[32];
    if (threadIdx.x < 32) lc[threadIdx.x] = 0;
    __syncthreads();
    int i = blockIdx.x * blockDim.x + threadIdx.x;
    if (i < nw) atomicAdd(&lc[lengths[i]], 1);
    __syncthreads();
    if (threadIdx.x < 25 && lc[threadIdx.x] > 0)
        atomicAdd(&ws[threadIdx.x], lc[threadIdx.x]);
}
__global__ void prefix_kernel(int* ws) {
    if (threadIdx.x == 0 && blockIdx.x == 0) {
        int acc = 0;
        for (int l = 0; l <= 24; ++l) { ws[25 + l] = acc; acc += ws[l]; }
    }
}
__global__ void scatter_kernel(const int* __restrict__ lengths, int* ws, int nw) {
    __shared__ int lcnt[32], lbase[32];
    if (threadIdx.x < 32) lcnt[threadIdx.x] = 0;
    __syncthreads();
    int i = blockIdx.x * blockDim.x + threadIdx.x;
    int l = 0, ticket = 0;
    bool act = i < nw;
    if (act) {
        l = lengths[i];
        ticket = atomicAdd(&lcnt[l], 1);
    }
    __syncthreads();
    if (threadIdx.x < 25 && lcnt[threadIdx.x] > 0)
        lbase[threadIdx.x] = atomicAdd(&ws[50 + threadIdx.x], lcnt[threadIdx.x]);
    __syncthreads();
    if (act) ws[100 + ws[25 + l] + lbase[l] + ticket] = i;
}

// ---------------- fused packing kernel ----------------
// Part 1: xtab[dir][v][m][s][q] bf16 = prescale*(b[row] + Wih[row]·emb[v]),
//   row = q*HID + j, j = off(s)+m (0 for pad rows).
// Part 2: h-part weight fragments wp[dir][m][kcp][lane][8], k=(kcp+2)*32+8*grp+i.
// Prescale: i,f,o rows by log2e; g rows by 2*log2e.
__global__ void pack_all_kernel(const float* __restrict__ emb,
                                const float* __restrict__ Wih_f, const float* __restrict__ Whh_f,
                                const float* __restrict__ b_f,
                                const float* __restrict__ Wih_b, const float* __restrict__ Whh_b,
                                const float* __restrict__ b_b,
                                unsigned short* __restrict__ xtab,
                                unsigned short* __restrict__ wp, int vocab) {
    int tid0 = blockIdx.x * blockDim.x + threadIdx.x;
    int xtTotal = 2 * vocab * NT * 16;
    if (tid0 < xtTotal) {
        int q = tid0 & 3, s = (tid0 >> 2) & 3;
        int m = (tid0 >> 4) % NT;
        int vv = (tid0 >> 4) / NT;          // dir*vocab + v
        int v = vv % vocab, dir = vv / vocab;
        int cnt_s = (s < 2) ? 13 : 12;
        float val = 0.0f;
        if (m < cnt_s) {
            int j = 13 * s - (s == 3 ? 1 : 0) + m;
            int row = q * HID + j;
            const float* W  = dir ? Wih_b : Wih_f;
            const float* bv = dir ? b_b   : b_f;
            float acc = bv[row];
            const float* wr = W + row * EMBD;
            const float* ev = emb + v * EMBD;
            for (int e = 0; e < EMBD; ++e) acc += wr[e] * ev[e];
            val = acc * ((q == 2) ? (2.0f * LOG2E) : LOG2E);
        }
        xtab[tid0] = f2bf(val);
        return;
    }
    int tid = tid0 - xtTotal;
    if (tid >= 2 * NT * 1024) return;
    int i    = tid & 7;
    int lane = (tid >> 3) & 63;
    int kcp  = (tid >> 9) & 1;
    int rem  = tid >> 10;
    int m    = rem % NT;
    int dir  = rem / NT;
    const float* Whh = dir ? Whh_b : Whh_f;

    int p = lane & 15, grp = lane >> 4;
    int k = (kcp + 2) * 32 + 8 * grp + i;
    int s = p >> 2, q = p & 3;
    int cnt_s = (s < 2) ? 13 : 12;
    float val = 0.0f;
    if (m < cnt_s) {
        int j = 13 * s - (s == 3 ? 1 : 0) + m;
        int row = q * HID + j;
        int kk = k - 64;
        int half = kk >> 5;
        int s2 = (kk >> 3) & 3;
        int r = kk & 7;
        int mcol = half * 8 + r;
        int cnt2 = (s2 < 2) ? 13 : 12;
        if (mcol < cnt2) {
            int jc = 13 * s2 - (s2 == 3 ? 1 : 0) + mcol;
            val = Whh[row * HID + jc] * ((q == 2) ? (2.0f * LOG2E) : LOG2E);
        }
    }
    wp[tid] = f2bf(val);
}

// ---------------- main MFMA kernel: h-part MFMA + x-part table ----------------
#define MFMA16(AW, BB, ACC) __builtin_amdgcn_mfma_f32_16x16x32_bf16((AW), (BB), (ACC), 0, 0, 0)

// Single-rcp gate update (see R19 notes). 5 exp2 + 2 rcp per element.
#define TTMH(M, XT, C, H) {                                        \
    const short8 w2 = *(const short8*)(sWl + ((M)*2+0)*512);       \
    const short8 w3 = *(const short8*)(sWl + ((M)*2+1)*512);       \
    f32x4 ah = zz;                                                 \
    ah = MFMA16(w2, bh0, ah);                                      \
    ah = MFMA16(w3, bh1, ah);                                      \
    float ai = ah[0] + __uint_as_float((XT).x << 16);              \
    float af = ah[1] + __uint_as_float((XT).x & 0xffff0000u);      \
    float ag = ah[2] + __uint_as_float((XT).y << 16);              \
    float ao = ah[3] + __uint_as_float((XT).y & 0xffff0000u);      \
    float ei = __builtin_amdgcn_exp2f(-ai);                        \
    float ef = __builtin_amdgcn_exp2f(-af);                        \
    float eg = __builtin_amdgcn_exp2f(ag);                         \
    float eo = __builtin_amdgcn_exp2f(-ao);                        \
    float a1 = 1.0f + ef, a2 = 1.0f + ei;                          \
    float a3 = eg + 1.0f, a4 = eg - 1.0f;                          \
    float p1 = a2 * a3;                                            \
    float nn = fmaf(a1, a4, (C) * p1);                             \
    float dd = a1 * p1;                                            \
    float cn = nn * __builtin_amdgcn_rcpf(dd);                     \
    float ec = __builtin_amdgcn_exp2f((2.0f * LOG2E) * cn);        \
    float b2 = ec + 1.0f, b3 = ec - 1.0f;                          \
    float qd = (1.0f + eo) * b2;                                   \
    float hn = b3 * __builtin_amdgcn_rcpf(qd);                     \
    (C) = upd ? cn : (C);                                          \
    (H) = upd ? hn : (H); }

__global__ __launch_bounds__(MBLK, 1)
void bilstm_mfma_kernel(const int* __restrict__ chars,
                        const int* __restrict__ lengths,
                        const int* __restrict__ perm,
                        const unsigned short* __restrict__ xtab,
                        const unsigned short* __restrict__ wp,
                        float* __restrict__ out, int nw, int ml, int vocab)
{
    const int dir = blockIdx.y;
    __shared__ unsigned short sW[NT * 2 * 512];   // 26 KB h-part fragments
    {
        const float4* src = (const float4*)(wp + dir * (NT * 2 * 512));
        float4* dst = (float4*)sW;
        for (int i = threadIdx.x; i < NT * 2 * 512 / 8; i += MBLK) dst[i] = src[i];
    }
    __syncthreads();

    const int lane = threadIdx.x & 63;
    const int wv   = threadIdx.x >> 6;   // 0..15
    const int wcol = lane & 15;
    const int s    = lane >> 4;

    int gidx = (blockIdx.x * 16 + wv) * 16 + wcol;
    gidx = imin(gidx, nw - 1);
    gidx = nw - 1 - gidx;        // LPT: longest words first
    const int word = perm[gidx];
    const int len  = lengths[word];

    int lmax = len;
    lmax = imax(lmax, __shfl_xor(lmax, 1));
    lmax = imax(lmax, __shfl_xor(lmax, 2));
    lmax = imax(lmax, __shfl_xor(lmax, 4));
    lmax = imax(lmax, __shfl_xor(lmax, 8));

    const int* charp = chars + (size_t)word * ml;
    const unsigned short* sWl = sW + lane * 8;
    const unsigned short* xdir = xtab + (size_t)dir * vocab * (NT * 16) + s * 4;

    const f32x4 zz = {0.0f, 0.0f, 0.0f, 0.0f};
    float c00=0,c01=0,c02=0,c03=0,c04=0,c05=0,c06=0,c07=0,c08=0,c09=0,c10=0,c11=0,c12=0;
    float h00=0,h01=0,h02=0,h03=0,h04=0,h05=0,h06=0,h07=0,h08=0,h09=0,h10=0,h11=0,h12=0;
    short8 bh0, bh1;
#pragma unroll
    for (int i2 = 0; i2 < 8; ++i2) { bh0[i2] = 0; bh1[i2] = 0; }

    int chcur = 0;
    if (lmax > 0) {
        int pos0 = dir ? imax(len - 1, 0) : 0;
        chcur = charp[pos0];
    }

    for (int t = 0; t < lmax; ++t) {
        const unsigned short* xb = xdir + (size_t)chcur * (NT * 16);
        uint2 xt0  = *(const uint2*)(xb + 0*16);
        uint2 xt1  = *(const uint2*)(xb + 1*16);
        uint2 xt2  = *(const uint2*)(xb + 2*16);
        uint2 xt3  = *(const uint2*)(xb + 3*16);
        uint2 xt4  = *(const uint2*)(xb + 4*16);
        uint2 xt5  = *(const uint2*)(xb + 5*16);
        uint2 xt6  = *(const uint2*)(xb + 6*16);
        uint2 xt7  = *(const uint2*)(xb + 7*16);
        uint2 xt8  = *(const uint2*)(xb + 8*16);
        uint2 xt9  = *(const uint2*)(xb + 9*16);
        uint2 xt10 = *(const uint2*)(xb + 10*16);
        uint2 xt11 = *(const uint2*)(xb + 11*16);
        uint2 xt12 = *(const uint2*)(xb + 12*16);

        int tn = (t + 1 < lmax) ? t + 1 : t;
        int posn = dir ? imax(len - 1 - tn, 0) : tn;
        int chnext = charp[posn];

        const bool upd = (t < len);
        TTMH(0,  xt0,  c00, h00)
        TTMH(1,  xt1,  c01, h01)
        TTMH(2,  xt2,  c02, h02)
        TTMH(3,  xt3,  c03, h03)
        TTMH(4,  xt4,  c04, h04)
        TTMH(5,  xt5,  c05, h05)
        TTMH(6,  xt6,  c06, h06)
        TTMH(7,  xt7,  c07, h07)
        TTMH(8,  xt8,  c08, h08)
        TTMH(9,  xt9,  c09, h09)
        TTMH(10, xt10, c10, h10)
        TTMH(11, xt11, c11, h11)
        TTMH(12, xt12, c12, h12)

        u32x4 p0, p1;
        p0[0] = cvtpk(h00, h01); p0[1] = cvtpk(h02, h03);
        p0[2] = cvtpk(h04, h05); p0[3] = cvtpk(h06, h07);
        p1[0] = cvtpk(h08, h09); p1[1] = cvtpk(h10, h11);
        p1[2] = cvtpk(h12, 0.0f); p1[3] = 0u;
        bh0 = __builtin_bit_cast(short8, p0);
        bh1 = __builtin_bit_cast(short8, p1);

        chcur = chnext;
    }

    int offs = 13 * s - (s == 3 ? 1 : 0);
    float* outw = out + (size_t)word * (2 * HID) + dir * HID + offs;
    outw[0] = h00; outw[1] = h01; outw[2]  = h02; outw[3]  = h03;
    outw[4] = h04; outw[5] = h05; outw[6]  = h06; outw[7]  = h07;
    outw[8] = h08; outw[9] = h09; outw[10] = h10; outw[11] = h11;
    if (s < 2) outw[12] = h12;
}

// ---------------- R1 fallback (scalar f32) ----------------
__global__ __launch_bounds__(BLK, 2)
void bilstm_fallback_kernel(const int* __restrict__ chars,
                            const int* __restrict__ lengths,
                            const float* __restrict__ emb,
                            const float* __restrict__ Wih_f, const float* __restrict__ Whh_f, const float* __restrict__ b_f,
                            const float* __restrict__ Wih_b, const float* __restrict__ Whh_b, const float* __restrict__ b_b,
                            const int* __restrict__ perm,
                            float* __restrict__ out, int nw, int ml)
{
    const int dir = blockIdx.y;
    const float* Wih = dir ? Wih_b : Wih_f;
    const float* Whh = dir ? Whh_b : Whh_f;
    const float* bv  = dir ? b_b  : b_f;
    __shared__ float4 sWU4[HID * 100];
    __shared__ float4 sB4[HID];
    {
        float* p = (float*)sWU4;
        for (int i = threadIdx.x; i < HID * 100 * 4; i += BLK) {
            int g = i & 3, r = i >> 2, j = r / 100, k = r - j * 100;
            p[i] = (k < EMBD) ? Wih[(j + g * HID) * EMBD + k]
                              : Whh[(j + g * HID) * HID + (k - EMBD)];
        }
        if (threadIdx.x < HID) {
            int j = threadIdx.x;
            sB4[j] = make_float4(bv[j], bv[j + HID], bv[j + 2*HID], bv[j + 3*HID]);
        }
    }
    __syncthreads();
    int gid = blockIdx.x * BLK + threadIdx.x;
    if (gid >= nw) return;
    int word = perm ? perm[gid] : gid;
    int len  = lengths[word];
    float h[HID], x[EMBD], c[HID], hn[HID];
#pragma unroll
    for (int j = 0; j < HID; ++j) h[j] = 0.f;
#pragma unroll 1
    for (int j = 0; j < HID; ++j) c[j] = 0.f;
    const int* wch = chars + word * ml;
    float* op = out + (size_t)word * (2 * HID) + dir * HID;
#pragma unroll 1
    for (int t = 0; t < len; ++t) {
        int pos = dir ? (len - 1 - t) : t;
        int ch = wch[pos];
        const float2* ep = (const float2*)(emb + ch * EMBD);
#pragma unroll
        for (int k = 0; k < EMBD / 2; ++k) { float2 v = ep[k]; x[2*k] = v.x; x[2*k+1] = v.y; }
#pragma unroll 1
        for (int j = 0; j < HID; ++j) {
            const float4* wpt = sWU4 + j * 100;
            float4 bb = sB4[j];
            float gi = bb.x, gf = bb.y, gg = bb.z, go = bb.w;
#pragma unroll
            for (int k = 0; k < EMBD; ++k) {
                float4 w = wpt[k]; float xv = x[k];
                gi += w.x*xv; gf += w.y*xv; gg += w.z*xv; go += w.w*xv;
            }
#pragma unroll
            for (int k = 0; k < HID; ++k) {
                float4 w = wpt[EMBD + k]; float hv = h[k];
                gi += w.x*hv; gf += w.y*hv; gg += w.z*hv; go += w.w*hv;
            }
            float cn = sigm(gf) * c[j] + sigm(gi) * tanhfast(gg);
            c[j] = cn;
            hn[j] = sigm(go) * tanhfast(cn);
        }
#pragma unroll
        for (int j = 0; j < HID; ++j) h[j] = hn[j];
    }
#pragma unroll
    for (int j = 0; j < HID / 2; ++j)
        ((float2*)op)[j] = make_float2(h[2*j], h[2*j+1]);
}

extern "C" void kernel_launch(void* const* d_in, const int* in_sizes, int n_in,
                              void* d_out, int out_size, void* d_ws, size_t ws_size,
                              hipStream_t stream) {
    const int*   chars = (const int*)  d_in[0];
    const int*   lens  = (const int*)  d_in[1];
    const float* emb   = (const float*)d_in[2];
    const float* Wih_f = (const float*)d_in[3];
    const float* Whh_f = (const float*)d_in[4];
    const float* b_f   = (const float*)d_in[5];
    const float* Wih_b = (const float*)d_in[6];
    const float* Whh_b = (const float*)d_in[7];
    const float* b_b   = (const float*)d_in[8];
    float* out = (float*)d_out;

    const int nw    = in_sizes[1];
    const int ml    = in_sizes[0] / nw;
    const int vocab = in_sizes[2] / EMBD;

    size_t sortNeed = (size_t)(100 + nw) * 4;
    size_t xtOff    = (sortNeed + 255) & ~(size_t)255;
    size_t xtBytes  = (size_t)2 * vocab * NT * 16 * 2;
    size_t wOff     = (xtOff + xtBytes + 1023) & ~(size_t)1023;
    size_t wBytes   = (size_t)2 * NT * 1024 * 2;
    size_t need     = wOff + wBytes;

    int* ws = (int*)d_ws;
    bool haveSort = ws_size >= sortNeed;
    if (haveSort) {
        zero_counts_kernel<<<1, 128, 0, stream>>>(ws);
        hist_kernel<<<(nw + 255) / 256, 256, 0, stream>>>(lens, ws, nw);
        prefix_kernel<<<1, 1, 0, stream>>>(ws);
        scatter_kernel<<<(nw + 255) / 256, 256, 0, stream>>>(lens, ws, nw);
    }

    if (ws_size >= need && haveSort) {
        unsigned short* xtab = (unsigned short*)((char*)d_ws + xtOff);
        unsigned short* wpk  = (unsigned short*)((char*)d_ws + wOff);
        int packTot = 2 * vocab * NT * 16 + 2 * NT * 1024;
        pack_all_kernel<<<(packTot + 255) / 256, 256, 0, stream>>>(
            emb, Wih_f, Whh_f, b_f, Wih_b, Whh_b, b_b, xtab, wpk, vocab);
        dim3 grid((nw + 255) / 256, 2);
        bilstm_mfma_kernel<<<grid, MBLK, 0, stream>>>(chars, lens, ws + 100, xtab, wpk,
                                                      out, nw, ml, vocab);
    } else {
        dim3 grid((nw + BLK - 1) / BLK, 2);
        bilstm_fallback_kernel<<<grid, BLK, 0, stream>>>(chars, lens, emb,
                                                         Wih_f, Whh_f, b_f,
                                                         Wih_b, Whh_b, b_b,
                                                         haveSort ? ws + 100 : nullptr,
                                                         out, nw, ml);
    }
}

// Round 25
// 218.798 us; speedup vs baseline: 2.4363x; 2.4363x over previous
//
#include <hip/hip_runtime.h>

#define EMBD 50
#define HID 50
#define BLK 256
#define NT 13               // gate tiles: 13*16 = 208 rows >= 200 real gates
#define LOG2E 1.44269504f

typedef float f32x4 __attribute__((ext_vector_type(4)));
typedef short short8 __attribute__((ext_vector_type(8)));
typedef unsigned u32x4 __attribute__((ext_vector_type(4)));

__device__ __forceinline__ int imax(int a, int b) { return a > b ? a : b; }
__device__ __forceinline__ int imin(int a, int b) { return a < b ? a : b; }

__device__ __forceinline__ unsigned short f2bf(float f) {
    unsigned u = __float_as_uint(f);
    u += 0x7FFFu + ((u >> 16) & 1u);
    return (unsigned short)(u >> 16);
}
__device__ __forceinline__ unsigned cvtpk(float a, float b) {
    unsigned r;
    asm("v_cvt_pk_bf16_f32 %0, %1, %2" : "=v"(r) : "v"(a), "v"(b));
    return r;
}
// (fallback only)
__device__ __forceinline__ float sigm(float x) {
    return __fdividef(1.0f, 1.0f + __expf(-x));
}
__device__ __forceinline__ float tanhfast(float x) {
    float e = __expf(2.0f * x);
    return 1.0f - __fdividef(2.0f, e + 1.0f);
}

// ---------------- length bucket sort ----------------
__global__ void zero_counts_kernel(int* ws) {
    if (threadIdx.x < 75) ws[threadIdx.x] = 0;
}
__global__ void hist_kernel(const int* __restrict__ lengths, int* ws, int nw) {
    __shared__ int lc[32];
    if (threadIdx.x < 32) lc[threadIdx.x] = 0;
    __syncthreads();
    int i = blockIdx.x * blockDim.x + threadIdx.x;
    if (i < nw) atomicAdd(&lc[lengths[i]], 1);
    __syncthreads();
    if (threadIdx.x < 25 && lc[threadIdx.x] > 0)
        atomicAdd(&ws[threadIdx.x], lc[threadIdx.x]);
}
__global__ void prefix_kernel(int* ws) {
    if (threadIdx.x == 0 && blockIdx.x == 0) {
        int acc = 0;
        for (int l = 0; l <= 24; ++l) { ws[25 + l] = acc; acc += ws[l]; }
    }
}
__global__ void scatter_kernel(const int* __restrict__ lengths, int* ws, int nw) {
    __shared__ int lcnt[32], lbase[32];
    if (threadIdx.x < 32) lcnt[threadIdx.x] = 0;
    __syncthreads();
    int i = blockIdx.x * blockDim.x + threadIdx.x;
    int l = 0, ticket = 0;
    bool act = i < nw;
    if (act) {
        l = lengths[i];
        ticket = atomicAdd(&lcnt[l], 1);
    }
    __syncthreads();
    if (threadIdx.x < 25 && lcnt[threadIdx.x] > 0)
        lbase[threadIdx.x] = atomicAdd(&ws[50 + threadIdx.x], lcnt[threadIdx.x]);
    __syncthreads();
    if (act) ws[100 + ws[25 + l] + lbase[l] + ticket] = i;
}

// ---------------- fused packing kernel ----------------
// Part 1: xtab[dir][v][m][s][q] bf16 = prescale*(b[row] + Wih[row]·emb[v]),
//   row = q*HID + j, j = off(s)+m (0 for pad rows).
// Part 2: h-part weight fragments wp[dir][m][kcp][lane][8], k=(kcp+2)*32+8*grp+i.
// Prescale: i,f,o rows by log2e; g rows by 2*log2e.
__global__ void pack_all_kernel(const float* __restrict__ emb,
                                const float* __restrict__ Wih_f, const float* __restrict__ Whh_f,
                                const float* __restrict__ b_f,
                                const float* __restrict__ Wih_b, const float* __restrict__ Whh_b,
                                const float* __restrict__ b_b,
                                unsigned short* __restrict__ xtab,
                                unsigned short* __restrict__ wp, int vocab) {
    int tid0 = blockIdx.x * blockDim.x + threadIdx.x;
    int xtTotal = 2 * vocab * NT * 16;
    if (tid0 < xtTotal) {
        int q = tid0 & 3, s = (tid0 >> 2) & 3;
        int m = (tid0 >> 4) % NT;
        int vv = (tid0 >> 4) / NT;          // dir*vocab + v
        int v = vv % vocab, dir = vv / vocab;
        int cnt_s = (s < 2) ? 13 : 12;
        float val = 0.0f;
        if (m < cnt_s) {
            int j = 13 * s - (s == 3 ? 1 : 0) + m;
            int row = q * HID + j;
            const float* W  = dir ? Wih_b : Wih_f;
            const float* bv = dir ? b_b   : b_f;
            float acc = bv[row];
            const float* wr = W + row * EMBD;
            const float* ev = emb + v * EMBD;
            for (int e = 0; e < EMBD; ++e) acc += wr[e] * ev[e];
            val = acc * ((q == 2) ? (2.0f * LOG2E) : LOG2E);
        }
        xtab[tid0] = f2bf(val);
        return;
    }
    int tid = tid0 - xtTotal;
    if (tid >= 2 * NT * 1024) return;
    int i    = tid & 7;
    int lane = (tid >> 3) & 63;
    int kcp  = (tid >> 9) & 1;
    int rem  = tid >> 10;
    int m    = rem % NT;
    int dir  = rem / NT;
    const float* Whh = dir ? Whh_b : Whh_f;

    int p = lane & 15, grp = lane >> 4;
    int k = (kcp + 2) * 32 + 8 * grp + i;
    int s = p >> 2, q = p & 3;
    int cnt_s = (s < 2) ? 13 : 12;
    float val = 0.0f;
    if (m < cnt_s) {
        int j = 13 * s - (s == 3 ? 1 : 0) + m;
        int row = q * HID + j;
        int kk = k - 64;
        int half = kk >> 5;
        int s2 = (kk >> 3) & 3;
        int r = kk & 7;
        int mcol = half * 8 + r;
        int cnt2 = (s2 < 2) ? 13 : 12;
        if (mcol < cnt2) {
            int jc = 13 * s2 - (s2 == 3 ? 1 : 0) + mcol;
            val = Whh[row * HID + jc] * ((q == 2) ? (2.0f * LOG2E) : LOG2E);
        }
    }
    wp[tid] = f2bf(val);
}

// ---------------- main MFMA kernel: h-part MFMA + x-part table ----------------
#define MFMA16(AW, BB, ACC) __builtin_amdgcn_mfma_f32_16x16x32_bf16((AW), (BB), (ACC), 0, 0, 0)

// Single-rcp gate update. Inputs prescaled (i,f,o: log2e; g: 2log2e):
//   cn = [c(1+ei)(eg+1) + (1+ef)(eg-1)] / [(1+ef)(1+ei)(eg+1)]
//   hn = (ec-1) / [(1+eo)(ec+1)],  ec = 2^(2log2e*cn)
// 5 exp2 + 2 rcp per element.
#define TTMH(M, XT, C, H) {                                        \
    const short8 w2 = *(const short8*)(sWl + ((M)*2+0)*512);       \
    const short8 w3 = *(const short8*)(sWl + ((M)*2+1)*512);       \
    f32x4 ah = zz;                                                 \
    ah = MFMA16(w2, bh0, ah);                                      \
    ah = MFMA16(w3, bh1, ah);                                      \
    float ai = ah[0] + __uint_as_float((XT).x << 16);              \
    float af = ah[1] + __uint_as_float((XT).x & 0xffff0000u);      \
    float ag = ah[2] + __uint_as_float((XT).y << 16);              \
    float ao = ah[3] + __uint_as_float((XT).y & 0xffff0000u);      \
    float ei = __builtin_amdgcn_exp2f(-ai);                        \
    float ef = __builtin_amdgcn_exp2f(-af);                        \
    float eg = __builtin_amdgcn_exp2f(ag);                         \
    float eo = __builtin_amdgcn_exp2f(-ao);                        \
    float a1 = 1.0f + ef, a2 = 1.0f + ei;                          \
    float a3 = eg + 1.0f, a4 = eg - 1.0f;                          \
    float p1 = a2 * a3;                                            \
    float nn = fmaf(a1, a4, (C) * p1);                             \
    float dd = a1 * p1;                                            \
    float cn = nn * __builtin_amdgcn_rcpf(dd);                     \
    float ec = __builtin_amdgcn_exp2f((2.0f * LOG2E) * cn);        \
    float b2 = ec + 1.0f, b3 = ec - 1.0f;                          \
    float qd = (1.0f + eo) * b2;                                   \
    float hn = b3 * __builtin_amdgcn_rcpf(qd);                     \
    (C) = upd ? cn : (C);                                          \
    (H) = upd ? hn : (H); }

__global__ __launch_bounds__(BLK, 2)
void bilstm_mfma_kernel(const int* __restrict__ chars,
                        const int* __restrict__ lengths,
                        const int* __restrict__ perm,
                        const unsigned short* __restrict__ xtab,
                        const unsigned short* __restrict__ wp,
                        float* __restrict__ out, int nw, int ml, int vocab)
{
    const int dir = blockIdx.y;
    __shared__ unsigned short sW[NT * 2 * 512];   // 26 KB h-part fragments
    {
        const float4* src = (const float4*)(wp + dir * (NT * 2 * 512));
        float4* dst = (float4*)sW;
        for (int i = threadIdx.x; i < NT * 2 * 512 / 8; i += BLK) dst[i] = src[i];
    }
    __syncthreads();

    const int lane = threadIdx.x & 63;
    const int wv   = threadIdx.x >> 6;
    const int wcol = lane & 15;
    const int s    = lane >> 4;

    int gidx = (blockIdx.x * 4 + wv) * 16 + wcol;
    gidx = imin(gidx, nw - 1);
    gidx = nw - 1 - gidx;        // LPT: longest words in block 0 (launch first)
    const int word = perm[gidx];
    const int len  = lengths[word];

    int lmax = len;
    lmax = imax(lmax, __shfl_xor(lmax, 1));
    lmax = imax(lmax, __shfl_xor(lmax, 2));
    lmax = imax(lmax, __shfl_xor(lmax, 4));
    lmax = imax(lmax, __shfl_xor(lmax, 8));

    const int* charp = chars + (size_t)word * ml;
    const unsigned short* sWl = sW + lane * 8;
    const unsigned short* xdir = xtab + (size_t)dir * vocab * (NT * 16) + s * 4;

    const f32x4 zz = {0.0f, 0.0f, 0.0f, 0.0f};
    float c00=0,c01=0,c02=0,c03=0,c04=0,c05=0,c06=0,c07=0,c08=0,c09=0,c10=0,c11=0,c12=0;
    float h00=0,h01=0,h02=0,h03=0,h04=0,h05=0,h06=0,h07=0,h08=0,h09=0,h10=0,h11=0,h12=0;
    short8 bh0, bh1;
#pragma unroll
    for (int i2 = 0; i2 < 8; ++i2) { bh0[i2] = 0; bh1[i2] = 0; }

    int chcur = 0;
    if (lmax > 0) {
        int pos0 = dir ? imax(len - 1, 0) : 0;
        chcur = charp[pos0];
    }

    for (int t = 0; t < lmax; ++t) {
        const unsigned short* xb = xdir + (size_t)chcur * (NT * 16);
        uint2 xt0  = *(const uint2*)(xb + 0*16);
        uint2 xt1  = *(const uint2*)(xb + 1*16);
        uint2 xt2  = *(const uint2*)(xb + 2*16);
        uint2 xt3  = *(const uint2*)(xb + 3*16);
        uint2 xt4  = *(const uint2*)(xb + 4*16);
        uint2 xt5  = *(const uint2*)(xb + 5*16);
        uint2 xt6  = *(const uint2*)(xb + 6*16);
        uint2 xt7  = *(const uint2*)(xb + 7*16);
        uint2 xt8  = *(const uint2*)(xb + 8*16);
        uint2 xt9  = *(const uint2*)(xb + 9*16);
        uint2 xt10 = *(const uint2*)(xb + 10*16);
        uint2 xt11 = *(const uint2*)(xb + 11*16);
        uint2 xt12 = *(const uint2*)(xb + 12*16);

        int tn = (t + 1 < lmax) ? t + 1 : t;
        int posn = dir ? imax(len - 1 - tn, 0) : tn;
        int chnext = charp[posn];

        const bool upd = (t < len);
        TTMH(0,  xt0,  c00, h00)
        TTMH(1,  xt1,  c01, h01)
        TTMH(2,  xt2,  c02, h02)
        TTMH(3,  xt3,  c03, h03)
        TTMH(4,  xt4,  c04, h04)
        TTMH(5,  xt5,  c05, h05)
        TTMH(6,  xt6,  c06, h06)
        TTMH(7,  xt7,  c07, h07)
        TTMH(8,  xt8,  c08, h08)
        TTMH(9,  xt9,  c09, h09)
        TTMH(10, xt10, c10, h10)
        TTMH(11, xt11, c11, h11)
        TTMH(12, xt12, c12, h12)

        u32x4 p0, p1;
        p0[0] = cvtpk(h00, h01); p0[1] = cvtpk(h02, h03);
        p0[2] = cvtpk(h04, h05); p0[3] = cvtpk(h06, h07);
        p1[0] = cvtpk(h08, h09); p1[1] = cvtpk(h10, h11);
        p1[2] = cvtpk(h12, 0.0f); p1[3] = 0u;
        bh0 = __builtin_bit_cast(short8, p0);
        bh1 = __builtin_bit_cast(short8, p1);

        chcur = chnext;
    }

    int offs = 13 * s - (s == 3 ? 1 : 0);
    float* outw = out + (size_t)word * (2 * HID) + dir * HID + offs;
    outw[0] = h00; outw[1] = h01; outw[2]  = h02; outw[3]  = h03;
    outw[4] = h04; outw[5] = h05; outw[6]  = h06; outw[7]  = h07;
    outw[8] = h08; outw[9] = h09; outw[10] = h10; outw[11] = h11;
    if (s < 2) outw[12] = h12;
}

// ---------------- R1 fallback (scalar f32) ----------------
__global__ __launch_bounds__(BLK, 2)
void bilstm_fallback_kernel(const int* __restrict__ chars,
                            const int* __restrict__ lengths,
                            const float* __restrict__ emb,
                            const float* __restrict__ Wih_f, const float* __restrict__ Whh_f, const float* __restrict__ b_f,
                            const float* __restrict__ Wih_b, const float* __restrict__ Whh_b, const float* __restrict__ b_b,
                            const int* __restrict__ perm,
                            float* __restrict__ out, int nw, int ml)
{
    const int dir = blockIdx.y;
    const float* Wih = dir ? Wih_b : Wih_f;
    const float* Whh = dir ? Whh_b : Whh_f;
    const float* bv  = dir ? b_b  : b_f;
    __shared__ float4 sWU4[HID * 100];
    __shared__ float4 sB4[HID];
    {
        float* p = (float*)sWU4;
        for (int i = threadIdx.x; i < HID * 100 * 4; i += BLK) {
            int g = i & 3, r = i >> 2, j = r / 100, k = r - j * 100;
            p[i] = (k < EMBD) ? Wih[(j + g * HID) * EMBD + k]
                              : Whh[(j + g * HID) * HID + (k - EMBD)];
        }
        if (threadIdx.x < HID) {
            int j = threadIdx.x;
            sB4[j] = make_float4(bv[j], bv[j + HID], bv[j + 2*HID], bv[j + 3*HID]);
        }
    }
    __syncthreads();
    int gid = blockIdx.x * BLK + threadIdx.x;
    if (gid >= nw) return;
    int word = perm ? perm[gid] : gid;
    int len  = lengths[word];
    float h[HID], x[EMBD], c[HID], hn[HID];
#pragma unroll
    for (int j = 0; j < HID; ++j) h[j] = 0.f;
#pragma unroll 1
    for (int j = 0; j < HID; ++j) c[j] = 0.f;
    const int* wch = chars + word * ml;
    float* op = out + (size_t)word * (2 * HID) + dir * HID;
#pragma unroll 1
    for (int t = 0; t < len; ++t) {
        int pos = dir ? (len - 1 - t) : t;
        int ch = wch[pos];
        const float2* ep = (const float2*)(emb + ch * EMBD);
#pragma unroll
        for (int k = 0; k < EMBD / 2; ++k) { float2 v = ep[k]; x[2*k] = v.x; x[2*k+1] = v.y; }
#pragma unroll 1
        for (int j = 0; j < HID; ++j) {
            const float4* wpt = sWU4 + j * 100;
            float4 bb = sB4[j];
            float gi = bb.x, gf = bb.y, gg = bb.z, go = bb.w;
#pragma unroll
            for (int k = 0; k < EMBD; ++k) {
                float4 w = wpt[k]; float xv = x[k];
                gi += w.x*xv; gf += w.y*xv; gg += w.z*xv; go += w.w*xv;
            }
#pragma unroll
            for (int k = 0; k < HID; ++k) {
                float4 w = wpt[EMBD + k]; float hv = h[k];
                gi += w.x*hv; gf += w.y*hv; gg += w.z*hv; go += w.w*hv;
            }
            float cn = sigm(gf) * c[j] + sigm(gi) * tanhfast(gg);
            c[j] = cn;
            hn[j] = sigm(go) * tanhfast(cn);
        }
#pragma unroll
        for (int j = 0; j < HID; ++j) h[j] = hn[j];
    }
#pragma unroll
    for (int j = 0; j < HID / 2; ++j)
        ((float2*)op)[j] = make_float2(h[2*j], h[2*j+1]);
}

extern "C" void kernel_launch(void* const* d_in, const int* in_sizes, int n_in,
                              void* d_out, int out_size, void* d_ws, size_t ws_size,
                              hipStream_t stream) {
    const int*   chars = (const int*)  d_in[0];
    const int*   lens  = (const int*)  d_in[1];
    const float* emb   = (const float*)d_in[2];
    const float* Wih_f = (const float*)d_in[3];
    const float* Whh_f = (const float*)d_in[4];
    const float* b_f   = (const float*)d_in[5];
    const float* Wih_b = (const float*)d_in[6];
    const float* Whh_b = (const float*)d_in[7];
    const float* b_b   = (const float*)d_in[8];
    float* out = (float*)d_out;

    const int nw    = in_sizes[1];
    const int ml    = in_sizes[0] / nw;
    const int vocab = in_sizes[2] / EMBD;

    size_t sortNeed = (size_t)(100 + nw) * 4;
    size_t xtOff    = (sortNeed + 255) & ~(size_t)255;
    size_t xtBytes  = (size_t)2 * vocab * NT * 16 * 2;
    size_t wOff     = (xtOff + xtBytes + 1023) & ~(size_t)1023;
    size_t wBytes   = (size_t)2 * NT * 1024 * 2;
    size_t need     = wOff + wBytes;

    int* ws = (int*)d_ws;
    bool haveSort = ws_size >= sortNeed;
    if (haveSort) {
        zero_counts_kernel<<<1, 128, 0, stream>>>(ws);
        hist_kernel<<<(nw + 255) / 256, 256, 0, stream>>>(lens, ws, nw);
        prefix_kernel<<<1, 1, 0, stream>>>(ws);
        scatter_kernel<<<(nw + 255) / 256, 256, 0, stream>>>(lens, ws, nw);
    }

    if (ws_size >= need && haveSort) {
        unsigned short* xtab = (unsigned short*)((char*)d_ws + xtOff);
        unsigned short* wpk  = (unsigned short*)((char*)d_ws + wOff);
        int packTot = 2 * vocab * NT * 16 + 2 * NT * 1024;
        pack_all_kernel<<<(packTot + 255) / 256, 256, 0, stream>>>(
            emb, Wih_f, Whh_f, b_f, Wih_b, Whh_b, b_b, xtab, wpk, vocab);
        dim3 grid((nw + 63) / 64, 2);
        bilstm_mfma_kernel<<<grid, BLK, 0, stream>>>(chars, lens, ws + 100, xtab, wpk,
                                                     out, nw, ml, vocab);
    } else {
        dim3 grid((nw + BLK - 1) / BLK, 2);
        bilstm_fallback_kernel<<<grid, BLK, 0, stream>>>(chars, lens, emb,
                                                         Wih_f, Whh_f, b_f,
                                                         Wih_b, Whh_b, b_b,
                                                         haveSort ? ws + 100 : nullptr,
                                                         out, nw, ml);
    }
}